// Round 3
// baseline (342.897 us; speedup 1.0000x reference)
//
#include <hip/hip_runtime.h>
#include <stdint.h>
#include <math.h>

#define B_ 8
#define S_ 1024
#define D0_ 128
#define D_ 256
#define H_ 8
#define HD_ 32
#define BH_ (B_*H_)

typedef __attribute__((ext_vector_type(8))) short short8;
typedef __attribute__((ext_vector_type(4))) float f32x4;
typedef __attribute__((ext_vector_type(4))) unsigned int u32x4;
typedef __attribute__((ext_vector_type(2))) float f32x2;

__device__ __forceinline__ unsigned short f2bf(float x) {
    unsigned int u = __float_as_uint(x);
    u += 0x7FFFu + ((u >> 16) & 1u);
    return (unsigned short)(u >> 16);
}
__device__ __forceinline__ float bf2f(unsigned short s) {
    return __uint_as_float(((unsigned int)s) << 16);
}

// ---------------- Kernel 1: projections (fp32 VALU GEMM) ----------------
__global__ __launch_bounds__(256) void proj_kernel(
    const float* __restrict__ query,
    const float* __restrict__ Wq, const float* __restrict__ Wk, const float* __restrict__ Wv,
    unsigned short* __restrict__ Qhi, unsigned short* __restrict__ Qlo,
    unsigned short* __restrict__ Khi, unsigned short* __restrict__ Klo,
    unsigned short* __restrict__ Vt)
{
    const int z = blockIdx.z;
    const float* W = (z == 0) ? Wq : (z == 1) ? Wk : Wv;
    const int m0 = blockIdx.x * 64;
    const int n0 = blockIdx.y * 64;
    __shared__ float xs[64 * 68];
    __shared__ float ws[64 * 68];
    const int t = threadIdx.x;
    const int ty = t >> 4, tx = t & 15;
    float acc[4][4] = {};
    for (int kc = 0; kc < 128; kc += 64) {
        #pragma unroll
        for (int it = 0; it < 4; ++it) {
            int fi = t + it * 256;
            int row = fi >> 4, c4 = fi & 15;
            *(float4*)(&xs[row * 68 + c4 * 4]) = *(const float4*)(&query[(size_t)(m0 + row) * 128 + kc + c4 * 4]);
            *(float4*)(&ws[row * 68 + c4 * 4]) = *(const float4*)(&W[(size_t)(n0 + row) * 128 + kc + c4 * 4]);
        }
        __syncthreads();
        #pragma unroll
        for (int k4 = 0; k4 < 16; ++k4) {
            float4 a4[4], b4[4];
            #pragma unroll
            for (int i = 0; i < 4; ++i) a4[i] = *(const float4*)(&xs[(ty * 4 + i) * 68 + k4 * 4]);
            #pragma unroll
            for (int j = 0; j < 4; ++j) b4[j] = *(const float4*)(&ws[(tx * 4 + j) * 68 + k4 * 4]);
            #pragma unroll
            for (int i = 0; i < 4; ++i)
                #pragma unroll
                for (int j = 0; j < 4; ++j)
                    acc[i][j] += a4[i].x * b4[j].x + a4[i].y * b4[j].y + a4[i].z * b4[j].z + a4[i].w * b4[j].w;
        }
        __syncthreads();
    }
    #pragma unroll
    for (int i = 0; i < 4; ++i) {
        int m = m0 + ty * 4 + i;
        int b = m >> 10, s = m & 1023;
        #pragma unroll
        for (int j = 0; j < 4; ++j) {
            int o = n0 + tx * 4 + j;
            int h = o >> 5, d = o & 31;
            int bh = b * 8 + h;
            float y = acc[i][j];
            if (z < 2) {
                unsigned short hi = f2bf(y);
                unsigned short lo = f2bf(y - bf2f(hi));
                size_t idx = ((size_t)(bh * 1024 + s)) * 32 + d;
                if (z == 0) { Qhi[idx] = hi; Qlo[idx] = lo; }
                else        { Khi[idx] = hi; Klo[idx] = lo; }
            } else {
                Vt[((size_t)(bh * 32 + d)) * 1024 + s] = f2bf(y);
            }
        }
    }
}

// ---------------- Kernel 1b: mask bias from Q row sums ----------------
__global__ void mask_kernel(const unsigned short* __restrict__ Qhi,
                            const unsigned short* __restrict__ Qlo,
                            float* __restrict__ maskbias)
{
    int r = blockIdx.x * blockDim.x + threadIdx.x;
    if (r >= BH_ * S_) return;
    const unsigned short* ph = Qhi + (size_t)r * 32;
    const unsigned short* pl = Qlo + (size_t)r * 32;
    float s = 0.f;
    #pragma unroll
    for (int d = 0; d < 32; ++d) s += bf2f(ph[d]) + bf2f(pl[d]);
    maskbias[r] = (s != 0.0f) ? 0.0f : -INFINITY;
}

// ---------------- Kernel 2: fused attention, register-resident P ----------------
// grid 4096 = 64 (b,h) x 64 q-tiles of 16 rows; block 256 = 4 waves.
// Wave w owns key strip [256w, 256w+256). QK^T swapped: mfma(K, Q) -> lane holds
// S^T[k][q], q = c = lane&15, k = kstrip + kf*16 + g*4 + r  (g = (lane>>4)&3).
// Softmax: flash combine across waves, ONE barrier.
// P stays in registers (packed bf16 pairs). PV B-frags built by in-wave
// ds_bpermute redistribution: B[j] = pk[2ch + (g>>1)][j&1] from lane
// c + 16*(2(g&1) + (j>>1)). Each wave computes its k-strip's O^T partial;
// 4-way cross-wave reduce in 9.2KB LDS.
__global__ __launch_bounds__(256, 6) void attn_kernel(
    const unsigned short* __restrict__ Qhi, const unsigned short* __restrict__ Qlo,
    const unsigned short* __restrict__ Khi, const unsigned short* __restrict__ Klo,
    const unsigned short* __restrict__ Vt, const float* __restrict__ maskbias,
    const float* __restrict__ U, float* __restrict__ attn_out, float* __restrict__ out_buf)
{
    __shared__ float Ored[4 * 16 * 36];     // [wave][q(16)][d(32)+pad4]
    __shared__ float redMS[4][2][16];       // per-wave (m_w, s_w) per q

    const int bid = blockIdx.x;
    const int swz = (bid & 7) * 512 + (bid >> 3);   // XCD-contiguous bh
    const int bh = swz >> 6;
    const int qbase = (swz & 63) << 4;
    const int tid = threadIdx.x;
    const int wid = tid >> 6;
    const int c = tid & 15;
    const int g = (tid >> 4) & 3;
    const int kstrip = wid << 8;

    const size_t bh_qk = (size_t)bh * S_ * 32;
    const size_t bh_u = (size_t)bh * S_ * S_;
    const int q = qbase + c;

    // Q fragment (B operand: col q = c, elements d = g*8..g*8+7)
    short8 qh = *(const short8*)(Qhi + bh_qk + (size_t)q * 32 + 8 * g);
    short8 ql = *(const short8*)(Qlo + bh_qk + (size_t)q * 32 + 8 * g);

    f32x4 s[16];
    #pragma unroll
    for (int kf = 0; kf < 16; ++kf) s[kf] = (f32x4){0.f, 0.f, 0.f, 0.f};

    // QK^T swapped, hi/lo split (3 MFMAs per kf)
    #pragma unroll
    for (int kf = 0; kf < 16; ++kf) {
        size_t koff = bh_qk + (size_t)(kstrip + kf * 16 + c) * 32 + 8 * g;
        short8 kh = *(const short8*)(Khi + koff);
        short8 kl = *(const short8*)(Klo + koff);
        s[kf] = __builtin_amdgcn_mfma_f32_16x16x32_bf16(kh, qh, s[kf], 0, 0, 0);
        s[kf] = __builtin_amdgcn_mfma_f32_16x16x32_bf16(kl, qh, s[kf], 0, 0, 0);
        s[kf] = __builtin_amdgcn_mfma_f32_16x16x32_bf16(kh, ql, s[kf], 0, 0, 0);
    }

    const float inv_scale = 0.17677669529663687f; // 1/sqrt(32)
    const float* Urow = U + bh_u + (size_t)q * S_;
    const float* mbrow = maskbias + bh * S_;
    #pragma unroll
    for (int kf = 0; kf < 16; ++kf) {
        int k0 = kstrip + kf * 16 + g * 4;
        f32x4 u = __builtin_nontemporal_load((const f32x4*)(Urow + k0));
        f32x4 mb = *(const f32x4*)(mbrow + k0);
        #pragma unroll
        for (int r = 0; r < 4; ++r)
            s[kf][r] = (s[kf][r] + u[r]) * inv_scale + mb[r];
    }

    // local (per-wave) softmax stats for this q = c
    float m = s[0][0];
    #pragma unroll
    for (int kf = 0; kf < 16; ++kf)
        #pragma unroll
        for (int r = 0; r < 4; ++r) m = fmaxf(m, s[kf][r]);
    m = fmaxf(m, __shfl_xor(m, 16, 64));
    m = fmaxf(m, __shfl_xor(m, 32, 64));
    m = fmaxf(m, -1e30f);   // guard fully-masked strip

    float sum = 0.f;
    #pragma unroll
    for (int kf = 0; kf < 16; ++kf)
        #pragma unroll
        for (int r = 0; r < 4; ++r) {
            float p = __expf(s[kf][r] - m);
            s[kf][r] = p;              // p_local
            sum += p;
        }
    sum += __shfl_xor(sum, 16, 64);
    sum += __shfl_xor(sum, 32, 64);
    if (g == 0) { redMS[wid][0][c] = m; redMS[wid][1][c] = sum; }
    __syncthreads();

    // flash combine across the 4 k-strips
    float m0 = redMS[0][0][c], m1 = redMS[1][0][c], m2 = redMS[2][0][c], m3 = redMS[3][0][c];
    float M = fmaxf(fmaxf(m0, m1), fmaxf(m2, m3));
    float S = redMS[0][1][c] * __expf(m0 - M) + redMS[1][1][c] * __expf(m1 - M)
            + redMS[2][1][c] * __expf(m2 - M) + redMS[3][1][c] * __expf(m3 - M);
    const float fw = __expf(m - M) / S;   // scale for this wave's p_local

    // normalize: nontemporal f32x4 attn stores + pack bf16 pairs into registers
    unsigned int pk[16][2];
    float* arow = attn_out + bh_u + (size_t)q * S_;
    #pragma unroll
    for (int kf = 0; kf < 16; ++kf) {
        int k0 = kstrip + kf * 16 + g * 4;
        f32x4 a;
        #pragma unroll
        for (int r = 0; r < 4; ++r) a[r] = s[kf][r] * fw;
        __builtin_nontemporal_store(a, (f32x4*)(arow + k0));
        pk[kf][0] = __builtin_amdgcn_perm(__float_as_uint(a[1]), __float_as_uint(a[0]), 0x07060302u);
        pk[kf][1] = __builtin_amdgcn_perm(__float_as_uint(a[3]), __float_as_uint(a[2]), 0x07060302u);
    }

    // PV over own k-strip; B-frags via in-wave bpermute redistribution
    const int srcA = c + 32 * (g & 1);   // lane c + 16*(2*(g&1))
    const int srcB = srcA + 16;
    const int gd2 = g >> 1;
    f32x4 o0 = (f32x4){0.f, 0.f, 0.f, 0.f};
    f32x4 o1 = (f32x4){0.f, 0.f, 0.f, 0.f};
    const unsigned short* vb0 = Vt + (size_t)(bh * 32 + c) * 1024 + kstrip;
    const unsigned short* vb1 = vb0 + 16 * 1024;
    #pragma unroll
    for (int ch = 0; ch < 8; ++ch) {
        short8 A0 = *(const short8*)(vb0 + ch * 32 + g * 8);
        short8 A1 = *(const short8*)(vb1 + ch * 32 + g * 8);
        unsigned int b0A = (unsigned int)__shfl((int)pk[2 * ch][0], srcA, 64);
        unsigned int b1A = (unsigned int)__shfl((int)pk[2 * ch][1], srcA, 64);
        unsigned int b0B = (unsigned int)__shfl((int)pk[2 * ch][0], srcB, 64);
        unsigned int b1B = (unsigned int)__shfl((int)pk[2 * ch][1], srcB, 64);
        unsigned int c0A = (unsigned int)__shfl((int)pk[2 * ch + 1][0], srcA, 64);
        unsigned int c1A = (unsigned int)__shfl((int)pk[2 * ch + 1][1], srcA, 64);
        unsigned int c0B = (unsigned int)__shfl((int)pk[2 * ch + 1][0], srcB, 64);
        unsigned int c1B = (unsigned int)__shfl((int)pk[2 * ch + 1][1], srcB, 64);
        union { u32x4 u; short8 h; } bb;
        bb.u[0] = gd2 ? c0A : b0A;
        bb.u[1] = gd2 ? c1A : b1A;
        bb.u[2] = gd2 ? c0B : b0B;
        bb.u[3] = gd2 ? c1B : b1B;
        o0 = __builtin_amdgcn_mfma_f32_16x16x32_bf16(A0, bb.h, o0, 0, 0, 0);
        o1 = __builtin_amdgcn_mfma_f32_16x16x32_bf16(A1, bb.h, o1, 0, 0, 0);
    }
    // partial O^T: lane holds q = c, d = g*4+r (o0) / 16+g*4+r (o1)
    *(f32x4*)(&Ored[(wid * 16 + c) * 36 + g * 4]) = o0;
    *(f32x4*)(&Ored[(wid * 16 + c) * 36 + 16 + g * 4]) = o1;
    __syncthreads();

    // final 4-way reduce + store: thread t -> q = t>>4, d-pair = (t&15)*2
    const int qq = tid >> 4;
    const int dd = (tid & 15) * 2;
    float v0 = 0.f, v1 = 0.f;
    #pragma unroll
    for (int w = 0; w < 4; ++w) {
        v0 += Ored[(w * 16 + qq) * 36 + dd];
        v1 += Ored[(w * 16 + qq) * 36 + dd + 1];
    }
    const int b = bh >> 3, h = bh & 7;
    f32x2 vv = {v0, v1};
    *(f32x2*)(out_buf + ((size_t)(b * 1024 + qbase + qq)) * 256 + h * 32 + dd) = vv;
}

// ---------------- Kernel 3: output projection ----------------
__global__ __launch_bounds__(256) void outproj_kernel(
    const float* __restrict__ xb, const float* __restrict__ Wo, float* __restrict__ outp)
{
    const int m0 = blockIdx.x * 64;
    const int n0 = blockIdx.y * 64;
    __shared__ float xs[64 * 68];
    __shared__ float ws[64 * 68];
    const int t = threadIdx.x;
    const int ty = t >> 4, tx = t & 15;
    float acc[4][4] = {};
    for (int kc = 0; kc < 256; kc += 64) {
        #pragma unroll
        for (int it = 0; it < 4; ++it) {
            int fi = t + it * 256;
            int row = fi >> 4, c4 = fi & 15;
            *(float4*)(&xs[row * 68 + c4 * 4]) = *(const float4*)(&xb[(size_t)(m0 + row) * 256 + kc + c4 * 4]);
            *(float4*)(&ws[row * 68 + c4 * 4]) = *(const float4*)(&Wo[(size_t)(n0 + row) * 256 + kc + c4 * 4]);
        }
        __syncthreads();
        #pragma unroll
        for (int k4 = 0; k4 < 16; ++k4) {
            float4 a4[4], b4[4];
            #pragma unroll
            for (int i = 0; i < 4; ++i) a4[i] = *(const float4*)(&xs[(ty * 4 + i) * 68 + k4 * 4]);
            #pragma unroll
            for (int j = 0; j < 4; ++j) b4[j] = *(const float4*)(&ws[(tx * 4 + j) * 68 + k4 * 4]);
            #pragma unroll
            for (int i = 0; i < 4; ++i)
                #pragma unroll
                for (int j = 0; j < 4; ++j)
                    acc[i][j] += a4[i].x * b4[j].x + a4[i].y * b4[j].y + a4[i].z * b4[j].z + a4[i].w * b4[j].w;
        }
        __syncthreads();
    }
    #pragma unroll
    for (int i = 0; i < 4; ++i)
        #pragma unroll
        for (int j = 0; j < 4; ++j)
            outp[(size_t)(m0 + ty * 4 + i) * 128 + n0 + tx * 4 + j] = acc[i][j];
}

extern "C" void kernel_launch(void* const* d_in, const int* in_sizes, int n_in,
                              void* d_out, int out_size, void* d_ws, size_t ws_size,
                              hipStream_t stream)
{
    const float* query = (const float*)d_in[0];
    const float* U     = (const float*)d_in[1];
    const float* Wq    = (const float*)d_in[2];
    const float* Wk    = (const float*)d_in[3];
    const float* Wv    = (const float*)d_in[4];
    const float* Wo    = (const float*)d_in[5];

    float* output = (float*)d_out;                                 // B*S*D0
    float* attn   = (float*)d_out + (size_t)B_ * S_ * D0_;         // B*H*S*S

    const size_t NQK = (size_t)BH_ * S_ * 32;
    unsigned short* Qhi = (unsigned short*)d_ws;
    unsigned short* Qlo = Qhi + NQK;
    unsigned short* Khi = Qlo + NQK;
    unsigned short* Klo = Khi + NQK;
    unsigned short* Vt  = Klo + NQK;
    float* maskbias = (float*)(Vt + NQK);
    float* out_buf  = maskbias + (size_t)BH_ * S_;

    proj_kernel<<<dim3(128, 4, 3), 256, 0, stream>>>(query, Wq, Wk, Wv, Qhi, Qlo, Khi, Klo, Vt);
    mask_kernel<<<dim3(256), 256, 0, stream>>>(Qhi, Qlo, maskbias);
    attn_kernel<<<dim3(4096), 256, 0, stream>>>(Qhi, Qlo, Khi, Klo, Vt, maskbias, U, attn, out_buf);
    outproj_kernel<<<dim3(128, 2), 256, 0, stream>>>(out_buf, Wo, output);
}

// Round 4
// 331.665 us; speedup vs baseline: 1.0339x; 1.0339x over previous
//
#include <hip/hip_runtime.h>
#include <stdint.h>
#include <math.h>

#define B_ 8
#define S_ 1024
#define D0_ 128
#define D_ 256
#define H_ 8
#define HD_ 32
#define BH_ (B_*H_)

typedef __attribute__((ext_vector_type(8))) short short8;
typedef __attribute__((ext_vector_type(4))) float f32x4;
typedef __attribute__((ext_vector_type(4))) unsigned int u32x4;
typedef __attribute__((ext_vector_type(2))) float f32x2;

__device__ __forceinline__ unsigned short f2bf(float x) {
    unsigned int u = __float_as_uint(x);
    u += 0x7FFFu + ((u >> 16) & 1u);
    return (unsigned short)(u >> 16);
}
__device__ __forceinline__ float bf2f(unsigned short s) {
    return __uint_as_float(((unsigned int)s) << 16);
}

// ---------------- Kernel 1: projections (fp32 VALU GEMM) ----------------
__global__ __launch_bounds__(256) void proj_kernel(
    const float* __restrict__ query,
    const float* __restrict__ Wq, const float* __restrict__ Wk, const float* __restrict__ Wv,
    unsigned short* __restrict__ Qhi, unsigned short* __restrict__ Qlo,
    unsigned short* __restrict__ Khi, unsigned short* __restrict__ Klo,
    unsigned short* __restrict__ Vt)
{
    const int z = blockIdx.z;
    const float* W = (z == 0) ? Wq : (z == 1) ? Wk : Wv;
    const int m0 = blockIdx.x * 64;
    const int n0 = blockIdx.y * 64;
    __shared__ float xs[64 * 68];
    __shared__ float ws[64 * 68];
    const int t = threadIdx.x;
    const int ty = t >> 4, tx = t & 15;
    float acc[4][4] = {};
    for (int kc = 0; kc < 128; kc += 64) {
        #pragma unroll
        for (int it = 0; it < 4; ++it) {
            int fi = t + it * 256;
            int row = fi >> 4, c4 = fi & 15;
            *(float4*)(&xs[row * 68 + c4 * 4]) = *(const float4*)(&query[(size_t)(m0 + row) * 128 + kc + c4 * 4]);
            *(float4*)(&ws[row * 68 + c4 * 4]) = *(const float4*)(&W[(size_t)(n0 + row) * 128 + kc + c4 * 4]);
        }
        __syncthreads();
        #pragma unroll
        for (int k4 = 0; k4 < 16; ++k4) {
            float4 a4[4], b4[4];
            #pragma unroll
            for (int i = 0; i < 4; ++i) a4[i] = *(const float4*)(&xs[(ty * 4 + i) * 68 + k4 * 4]);
            #pragma unroll
            for (int j = 0; j < 4; ++j) b4[j] = *(const float4*)(&ws[(tx * 4 + j) * 68 + k4 * 4]);
            #pragma unroll
            for (int i = 0; i < 4; ++i)
                #pragma unroll
                for (int j = 0; j < 4; ++j)
                    acc[i][j] += a4[i].x * b4[j].x + a4[i].y * b4[j].y + a4[i].z * b4[j].z + a4[i].w * b4[j].w;
        }
        __syncthreads();
    }
    #pragma unroll
    for (int i = 0; i < 4; ++i) {
        int m = m0 + ty * 4 + i;
        int b = m >> 10, s = m & 1023;
        #pragma unroll
        for (int j = 0; j < 4; ++j) {
            int o = n0 + tx * 4 + j;
            int h = o >> 5, d = o & 31;
            int bh = b * 8 + h;
            float y = acc[i][j];
            if (z < 2) {
                unsigned short hi = f2bf(y);
                unsigned short lo = f2bf(y - bf2f(hi));
                size_t idx = ((size_t)(bh * 1024 + s)) * 32 + d;
                if (z == 0) { Qhi[idx] = hi; Qlo[idx] = lo; }
                else        { Khi[idx] = hi; Klo[idx] = lo; }
            } else {
                Vt[((size_t)(bh * 32 + d)) * 1024 + s] = f2bf(y);
            }
        }
    }
}

// ---------------- Kernel 1b: mask bias from Q row sums ----------------
__global__ void mask_kernel(const unsigned short* __restrict__ Qhi,
                            const unsigned short* __restrict__ Qlo,
                            float* __restrict__ maskbias)
{
    int r = blockIdx.x * blockDim.x + threadIdx.x;
    if (r >= BH_ * S_) return;
    const unsigned short* ph = Qhi + (size_t)r * 32;
    const unsigned short* pl = Qlo + (size_t)r * 32;
    float s = 0.f;
    #pragma unroll
    for (int d = 0; d < 32; ++d) s += bf2f(ph[d]) + bf2f(pl[d]);
    maskbias[r] = (s != 0.0f) ? 0.0f : -INFINITY;
}

// ---------------- Kernel 2: fused attention, register-resident P ----------------
// grid 4096 = 64 (b,h) x 64 q-tiles of 16 rows; block 256 = 4 waves.
// Wave w owns key strip [256w, 256w+256). QK^T swapped: mfma(K, Q) -> lane holds
// S^T[k][q], q = c = lane&15, k = kstrip + kf*16 + g*4 + r  (g = (lane>>4)&3).
// Softmax: flash combine across waves, ONE barrier.
// P stays in registers (packed bf16 pairs). PV B-frags built by in-wave
// shfl redistribution. 4-way cross-wave O reduce in 9.2KB LDS.
// NOTE (R3 post-mortem): NO nontemporal hints — NT store amplified WRITE
// 281->514MB (16B/lane partial-line evictions), NT load of U defeated L3
// retention (FETCH +117MB). Plain loads/stores restore write-combine + L3.
__global__ __launch_bounds__(256, 6) void attn_kernel(
    const unsigned short* __restrict__ Qhi, const unsigned short* __restrict__ Qlo,
    const unsigned short* __restrict__ Khi, const unsigned short* __restrict__ Klo,
    const unsigned short* __restrict__ Vt, const float* __restrict__ maskbias,
    const float* __restrict__ U, float* __restrict__ attn_out, float* __restrict__ out_buf)
{
    __shared__ float Ored[4 * 16 * 36];     // [wave][q(16)][d(32)+pad4]
    __shared__ float redMS[4][2][16];       // per-wave (m_w, s_w) per q

    const int bid = blockIdx.x;
    const int swz = (bid & 7) * 512 + (bid >> 3);   // XCD-contiguous bh
    const int bh = swz >> 6;
    const int qbase = (swz & 63) << 4;
    const int tid = threadIdx.x;
    const int wid = tid >> 6;
    const int c = tid & 15;
    const int g = (tid >> 4) & 3;
    const int kstrip = wid << 8;

    const size_t bh_qk = (size_t)bh * S_ * 32;
    const size_t bh_u = (size_t)bh * S_ * S_;
    const int q = qbase + c;

    // Q fragment (B operand: col q = c, elements d = g*8..g*8+7)
    short8 qh = *(const short8*)(Qhi + bh_qk + (size_t)q * 32 + 8 * g);
    short8 ql = *(const short8*)(Qlo + bh_qk + (size_t)q * 32 + 8 * g);

    f32x4 s[16];
    #pragma unroll
    for (int kf = 0; kf < 16; ++kf) s[kf] = (f32x4){0.f, 0.f, 0.f, 0.f};

    // QK^T swapped, hi/lo split (3 MFMAs per kf)
    #pragma unroll
    for (int kf = 0; kf < 16; ++kf) {
        size_t koff = bh_qk + (size_t)(kstrip + kf * 16 + c) * 32 + 8 * g;
        short8 kh = *(const short8*)(Khi + koff);
        short8 kl = *(const short8*)(Klo + koff);
        s[kf] = __builtin_amdgcn_mfma_f32_16x16x32_bf16(kh, qh, s[kf], 0, 0, 0);
        s[kf] = __builtin_amdgcn_mfma_f32_16x16x32_bf16(kl, qh, s[kf], 0, 0, 0);
        s[kf] = __builtin_amdgcn_mfma_f32_16x16x32_bf16(kh, ql, s[kf], 0, 0, 0);
    }

    const float inv_scale = 0.17677669529663687f; // 1/sqrt(32)
    const float* Urow = U + bh_u + (size_t)q * S_;
    const float* mbrow = maskbias + bh * S_;
    #pragma unroll
    for (int kf = 0; kf < 16; ++kf) {
        int k0 = kstrip + kf * 16 + g * 4;
        f32x4 u = *(const f32x4*)(Urow + k0);
        f32x4 mb = *(const f32x4*)(mbrow + k0);
        #pragma unroll
        for (int r = 0; r < 4; ++r)
            s[kf][r] = (s[kf][r] + u[r]) * inv_scale + mb[r];
    }

    // local (per-wave) softmax stats for this q = c
    float m = s[0][0];
    #pragma unroll
    for (int kf = 0; kf < 16; ++kf)
        #pragma unroll
        for (int r = 0; r < 4; ++r) m = fmaxf(m, s[kf][r]);
    m = fmaxf(m, __shfl_xor(m, 16, 64));
    m = fmaxf(m, __shfl_xor(m, 32, 64));
    m = fmaxf(m, -1e30f);   // guard fully-masked strip

    float sum = 0.f;
    #pragma unroll
    for (int kf = 0; kf < 16; ++kf)
        #pragma unroll
        for (int r = 0; r < 4; ++r) {
            float p = __expf(s[kf][r] - m);
            s[kf][r] = p;              // p_local
            sum += p;
        }
    sum += __shfl_xor(sum, 16, 64);
    sum += __shfl_xor(sum, 32, 64);
    if (g == 0) { redMS[wid][0][c] = m; redMS[wid][1][c] = sum; }
    __syncthreads();

    // flash combine across the 4 k-strips
    float m0 = redMS[0][0][c], m1 = redMS[1][0][c], m2 = redMS[2][0][c], m3 = redMS[3][0][c];
    float M = fmaxf(fmaxf(m0, m1), fmaxf(m2, m3));
    float S = redMS[0][1][c] * __expf(m0 - M) + redMS[1][1][c] * __expf(m1 - M)
            + redMS[2][1][c] * __expf(m2 - M) + redMS[3][1][c] * __expf(m3 - M);
    const float fw = __expf(m - M) / S;   // scale for this wave's p_local

    // normalize: f32x4 attn stores + pack bf16 pairs into registers
    unsigned int pk[16][2];
    float* arow = attn_out + bh_u + (size_t)q * S_;
    #pragma unroll
    for (int kf = 0; kf < 16; ++kf) {
        int k0 = kstrip + kf * 16 + g * 4;
        f32x4 a;
        #pragma unroll
        for (int r = 0; r < 4; ++r) a[r] = s[kf][r] * fw;
        *(f32x4*)(arow + k0) = a;
        pk[kf][0] = __builtin_amdgcn_perm(__float_as_uint(a[1]), __float_as_uint(a[0]), 0x07060302u);
        pk[kf][1] = __builtin_amdgcn_perm(__float_as_uint(a[3]), __float_as_uint(a[2]), 0x07060302u);
    }

    // PV over own k-strip; B-frags via in-wave shfl redistribution
    const int srcA = c + 32 * (g & 1);   // lane c + 16*(2*(g&1))
    const int srcB = srcA + 16;
    const int gd2 = g >> 1;
    f32x4 o0 = (f32x4){0.f, 0.f, 0.f, 0.f};
    f32x4 o1 = (f32x4){0.f, 0.f, 0.f, 0.f};
    const unsigned short* vb0 = Vt + (size_t)(bh * 32 + c) * 1024 + kstrip;
    const unsigned short* vb1 = vb0 + 16 * 1024;
    #pragma unroll
    for (int ch = 0; ch < 8; ++ch) {
        short8 A0 = *(const short8*)(vb0 + ch * 32 + g * 8);
        short8 A1 = *(const short8*)(vb1 + ch * 32 + g * 8);
        unsigned int b0A = (unsigned int)__shfl((int)pk[2 * ch][0], srcA, 64);
        unsigned int b1A = (unsigned int)__shfl((int)pk[2 * ch][1], srcA, 64);
        unsigned int b0B = (unsigned int)__shfl((int)pk[2 * ch][0], srcB, 64);
        unsigned int b1B = (unsigned int)__shfl((int)pk[2 * ch][1], srcB, 64);
        unsigned int c0A = (unsigned int)__shfl((int)pk[2 * ch + 1][0], srcA, 64);
        unsigned int c1A = (unsigned int)__shfl((int)pk[2 * ch + 1][1], srcA, 64);
        unsigned int c0B = (unsigned int)__shfl((int)pk[2 * ch + 1][0], srcB, 64);
        unsigned int c1B = (unsigned int)__shfl((int)pk[2 * ch + 1][1], srcB, 64);
        union { u32x4 u; short8 h; } bb;
        bb.u[0] = gd2 ? c0A : b0A;
        bb.u[1] = gd2 ? c1A : b1A;
        bb.u[2] = gd2 ? c0B : b0B;
        bb.u[3] = gd2 ? c1B : b1B;
        o0 = __builtin_amdgcn_mfma_f32_16x16x32_bf16(A0, bb.h, o0, 0, 0, 0);
        o1 = __builtin_amdgcn_mfma_f32_16x16x32_bf16(A1, bb.h, o1, 0, 0, 0);
    }
    // partial O^T: lane holds q = c, d = g*4+r (o0) / 16+g*4+r (o1)
    *(f32x4*)(&Ored[(wid * 16 + c) * 36 + g * 4]) = o0;
    *(f32x4*)(&Ored[(wid * 16 + c) * 36 + 16 + g * 4]) = o1;
    __syncthreads();

    // final 4-way reduce + store: thread t -> q = t>>4, d-pair = (t&15)*2
    const int qq = tid >> 4;
    const int dd = (tid & 15) * 2;
    float v0 = 0.f, v1 = 0.f;
    #pragma unroll
    for (int w = 0; w < 4; ++w) {
        v0 += Ored[(w * 16 + qq) * 36 + dd];
        v1 += Ored[(w * 16 + qq) * 36 + dd + 1];
    }
    const int b = bh >> 3, h = bh & 7;
    f32x2 vv = {v0, v1};
    *(f32x2*)(out_buf + ((size_t)(b * 1024 + qbase + qq)) * 256 + h * 32 + dd) = vv;
}

// ---------------- Kernel 3: output projection ----------------
__global__ __launch_bounds__(256) void outproj_kernel(
    const float* __restrict__ xb, const float* __restrict__ Wo, float* __restrict__ outp)
{
    const int m0 = blockIdx.x * 64;
    const int n0 = blockIdx.y * 64;
    __shared__ float xs[64 * 68];
    __shared__ float ws[64 * 68];
    const int t = threadIdx.x;
    const int ty = t >> 4, tx = t & 15;
    float acc[4][4] = {};
    for (int kc = 0; kc < 256; kc += 64) {
        #pragma unroll
        for (int it = 0; it < 4; ++it) {
            int fi = t + it * 256;
            int row = fi >> 4, c4 = fi & 15;
            *(float4*)(&xs[row * 68 + c4 * 4]) = *(const float4*)(&xb[(size_t)(m0 + row) * 256 + kc + c4 * 4]);
            *(float4*)(&ws[row * 68 + c4 * 4]) = *(const float4*)(&Wo[(size_t)(n0 + row) * 256 + kc + c4 * 4]);
        }
        __syncthreads();
        #pragma unroll
        for (int k4 = 0; k4 < 16; ++k4) {
            float4 a4[4], b4[4];
            #pragma unroll
            for (int i = 0; i < 4; ++i) a4[i] = *(const float4*)(&xs[(ty * 4 + i) * 68 + k4 * 4]);
            #pragma unroll
            for (int j = 0; j < 4; ++j) b4[j] = *(const float4*)(&ws[(tx * 4 + j) * 68 + k4 * 4]);
            #pragma unroll
            for (int i = 0; i < 4; ++i)
                #pragma unroll
                for (int j = 0; j < 4; ++j)
                    acc[i][j] += a4[i].x * b4[j].x + a4[i].y * b4[j].y + a4[i].z * b4[j].z + a4[i].w * b4[j].w;
        }
        __syncthreads();
    }
    #pragma unroll
    for (int i = 0; i < 4; ++i)
        #pragma unroll
        for (int j = 0; j < 4; ++j)
            outp[(size_t)(m0 + ty * 4 + i) * 128 + n0 + tx * 4 + j] = acc[i][j];
}

extern "C" void kernel_launch(void* const* d_in, const int* in_sizes, int n_in,
                              void* d_out, int out_size, void* d_ws, size_t ws_size,
                              hipStream_t stream)
{
    const float* query = (const float*)d_in[0];
    const float* U     = (const float*)d_in[1];
    const float* Wq    = (const float*)d_in[2];
    const float* Wk    = (const float*)d_in[3];
    const float* Wv    = (const float*)d_in[4];
    const float* Wo    = (const float*)d_in[5];

    float* output = (float*)d_out;                                 // B*S*D0
    float* attn   = (float*)d_out + (size_t)B_ * S_ * D0_;         // B*H*S*S

    const size_t NQK = (size_t)BH_ * S_ * 32;
    unsigned short* Qhi = (unsigned short*)d_ws;
    unsigned short* Qlo = Qhi + NQK;
    unsigned short* Khi = Qlo + NQK;
    unsigned short* Klo = Khi + NQK;
    unsigned short* Vt  = Klo + NQK;
    float* maskbias = (float*)(Vt + NQK);
    float* out_buf  = maskbias + (size_t)BH_ * S_;

    proj_kernel<<<dim3(128, 4, 3), 256, 0, stream>>>(query, Wq, Wk, Wv, Qhi, Qlo, Khi, Klo, Vt);
    mask_kernel<<<dim3(256), 256, 0, stream>>>(Qhi, Qlo, maskbias);
    attn_kernel<<<dim3(4096), 256, 0, stream>>>(Qhi, Qlo, Khi, Klo, Vt, maskbias, U, attn, out_buf);
    outproj_kernel<<<dim3(128, 2), 256, 0, stream>>>(out_buf, Wo, output);
}

// Round 5
// 271.716 us; speedup vs baseline: 1.2620x; 1.2206x over previous
//
#include <hip/hip_runtime.h>
#include <stdint.h>
#include <math.h>

#define B_ 8
#define S_ 1024
#define D0_ 128
#define D_ 256
#define H_ 8
#define HD_ 32
#define BH_ (B_*H_)

typedef __attribute__((ext_vector_type(8))) short short8;
typedef __attribute__((ext_vector_type(4))) float f32x4;
typedef __attribute__((ext_vector_type(4))) unsigned int u32x4;
typedef __attribute__((ext_vector_type(2))) float f32x2;

__device__ __forceinline__ unsigned short f2bf(float x) {
    unsigned int u = __float_as_uint(x);
    u += 0x7FFFu + ((u >> 16) & 1u);
    return (unsigned short)(u >> 16);
}
__device__ __forceinline__ float bf2f(unsigned short s) {
    return __uint_as_float(((unsigned int)s) << 16);
}

// ---------------- Kernel 1: projections (fp32 VALU GEMM) ----------------
__global__ __launch_bounds__(256) void proj_kernel(
    const float* __restrict__ query,
    const float* __restrict__ Wq, const float* __restrict__ Wk, const float* __restrict__ Wv,
    unsigned short* __restrict__ Qhi, unsigned short* __restrict__ Qlo,
    unsigned short* __restrict__ Khi, unsigned short* __restrict__ Klo,
    unsigned short* __restrict__ Vt)
{
    const int z = blockIdx.z;
    const float* W = (z == 0) ? Wq : (z == 1) ? Wk : Wv;
    const int m0 = blockIdx.x * 64;
    const int n0 = blockIdx.y * 64;
    __shared__ float xs[64 * 68];
    __shared__ float ws[64 * 68];
    const int t = threadIdx.x;
    const int ty = t >> 4, tx = t & 15;
    float acc[4][4] = {};
    for (int kc = 0; kc < 128; kc += 64) {
        #pragma unroll
        for (int it = 0; it < 4; ++it) {
            int fi = t + it * 256;
            int row = fi >> 4, c4 = fi & 15;
            *(float4*)(&xs[row * 68 + c4 * 4]) = *(const float4*)(&query[(size_t)(m0 + row) * 128 + kc + c4 * 4]);
            *(float4*)(&ws[row * 68 + c4 * 4]) = *(const float4*)(&W[(size_t)(n0 + row) * 128 + kc + c4 * 4]);
        }
        __syncthreads();
        #pragma unroll
        for (int k4 = 0; k4 < 16; ++k4) {
            float4 a4[4], b4[4];
            #pragma unroll
            for (int i = 0; i < 4; ++i) a4[i] = *(const float4*)(&xs[(ty * 4 + i) * 68 + k4 * 4]);
            #pragma unroll
            for (int j = 0; j < 4; ++j) b4[j] = *(const float4*)(&ws[(tx * 4 + j) * 68 + k4 * 4]);
            #pragma unroll
            for (int i = 0; i < 4; ++i)
                #pragma unroll
                for (int j = 0; j < 4; ++j)
                    acc[i][j] += a4[i].x * b4[j].x + a4[i].y * b4[j].y + a4[i].z * b4[j].z + a4[i].w * b4[j].w;
        }
        __syncthreads();
    }
    #pragma unroll
    for (int i = 0; i < 4; ++i) {
        int m = m0 + ty * 4 + i;
        int b = m >> 10, s = m & 1023;
        #pragma unroll
        for (int j = 0; j < 4; ++j) {
            int o = n0 + tx * 4 + j;
            int h = o >> 5, d = o & 31;
            int bh = b * 8 + h;
            float y = acc[i][j];
            if (z < 2) {
                unsigned short hi = f2bf(y);
                unsigned short lo = f2bf(y - bf2f(hi));
                size_t idx = ((size_t)(bh * 1024 + s)) * 32 + d;
                if (z == 0) { Qhi[idx] = hi; Qlo[idx] = lo; }
                else        { Khi[idx] = hi; Klo[idx] = lo; }
            } else {
                Vt[((size_t)(bh * 32 + d)) * 1024 + s] = f2bf(y);
            }
        }
    }
}

// ---------------- Kernel 1b: mask bias from Q row sums ----------------
__global__ void mask_kernel(const unsigned short* __restrict__ Qhi,
                            const unsigned short* __restrict__ Qlo,
                            float* __restrict__ maskbias)
{
    int r = blockIdx.x * blockDim.x + threadIdx.x;
    if (r >= BH_ * S_) return;
    const unsigned short* ph = Qhi + (size_t)r * 32;
    const unsigned short* pl = Qlo + (size_t)r * 32;
    float s = 0.f;
    #pragma unroll
    for (int d = 0; d < 32; ++d) s += bf2f(ph[d]) + bf2f(pl[d]);
    maskbias[r] = (s != 0.0f) ? 0.0f : -INFINITY;
}

// ---------------- Kernel 2: fused attention, register-resident P ----------------
// grid 4096 = 64 (b,h) x 64 q-tiles of 16 rows; block 256 = 4 waves.
// Wave w owns key strip [256w, 256w+256). QK^T swapped: mfma(K, Q) -> lane holds
// S^T[k][q], q = c = lane&15, k = kstrip + kf*16 + g*4 + r  (g = (lane>>4)&3).
// Softmax: flash combine across waves, ONE barrier.
// PV fused per-chunk: normalize -> attn store -> pack -> shfl redistribute ->
// MFMA, consuming s[] in place (no persistent pk[] array).
// R4 post-mortem: __launch_bounds__(256,6) forced <=85 VGPR -> scratch spill
// (VGPR_Count 40, WRITE +168MB of spill evictions). (256,4) gives 128-reg
// budget; peak live set ~100 regs -> no spill, 4 blocks/CU.
__global__ __launch_bounds__(256, 4) void attn_kernel(
    const unsigned short* __restrict__ Qhi, const unsigned short* __restrict__ Qlo,
    const unsigned short* __restrict__ Khi, const unsigned short* __restrict__ Klo,
    const unsigned short* __restrict__ Vt, const float* __restrict__ maskbias,
    const float* __restrict__ U, float* __restrict__ attn_out, float* __restrict__ out_buf)
{
    __shared__ float Ored[4 * 16 * 36];     // [wave][q(16)][d(32)+pad4]
    __shared__ float redMS[4][2][16];       // per-wave (m_w, s_w) per q

    const int bid = blockIdx.x;
    const int swz = (bid & 7) * 512 + (bid >> 3);   // XCD-contiguous bh
    const int bh = swz >> 6;
    const int qbase = (swz & 63) << 4;
    const int tid = threadIdx.x;
    const int wid = tid >> 6;
    const int c = tid & 15;
    const int g = (tid >> 4) & 3;
    const int kstrip = wid << 8;

    const size_t bh_qk = (size_t)bh * S_ * 32;
    const size_t bh_u = (size_t)bh * S_ * S_;
    const int q = qbase + c;

    // Q fragment (B operand: col q = c, elements d = g*8..g*8+7)
    short8 qh = *(const short8*)(Qhi + bh_qk + (size_t)q * 32 + 8 * g);
    short8 ql = *(const short8*)(Qlo + bh_qk + (size_t)q * 32 + 8 * g);

    f32x4 s[16];
    #pragma unroll
    for (int kf = 0; kf < 16; ++kf) s[kf] = (f32x4){0.f, 0.f, 0.f, 0.f};

    // QK^T swapped, hi/lo split (3 MFMAs per kf)
    #pragma unroll
    for (int kf = 0; kf < 16; ++kf) {
        size_t koff = bh_qk + (size_t)(kstrip + kf * 16 + c) * 32 + 8 * g;
        short8 kh = *(const short8*)(Khi + koff);
        short8 kl = *(const short8*)(Klo + koff);
        s[kf] = __builtin_amdgcn_mfma_f32_16x16x32_bf16(kh, qh, s[kf], 0, 0, 0);
        s[kf] = __builtin_amdgcn_mfma_f32_16x16x32_bf16(kl, qh, s[kf], 0, 0, 0);
        s[kf] = __builtin_amdgcn_mfma_f32_16x16x32_bf16(kh, ql, s[kf], 0, 0, 0);
    }

    const float inv_scale = 0.17677669529663687f; // 1/sqrt(32)
    const float* Urow = U + bh_u + (size_t)q * S_;
    const float* mbrow = maskbias + bh * S_;
    #pragma unroll
    for (int kf = 0; kf < 16; ++kf) {
        int k0 = kstrip + kf * 16 + g * 4;
        f32x4 u = *(const f32x4*)(Urow + k0);
        f32x4 mb = *(const f32x4*)(mbrow + k0);
        #pragma unroll
        for (int r = 0; r < 4; ++r)
            s[kf][r] = (s[kf][r] + u[r]) * inv_scale + mb[r];
    }

    // local (per-wave) softmax stats for this q = c
    float m = s[0][0];
    #pragma unroll
    for (int kf = 0; kf < 16; ++kf)
        #pragma unroll
        for (int r = 0; r < 4; ++r) m = fmaxf(m, s[kf][r]);
    m = fmaxf(m, __shfl_xor(m, 16, 64));
    m = fmaxf(m, __shfl_xor(m, 32, 64));
    m = fmaxf(m, -1e30f);   // guard fully-masked strip

    float sum = 0.f;
    #pragma unroll
    for (int kf = 0; kf < 16; ++kf)
        #pragma unroll
        for (int r = 0; r < 4; ++r) {
            float p = __expf(s[kf][r] - m);
            s[kf][r] = p;              // p_local
            sum += p;
        }
    sum += __shfl_xor(sum, 16, 64);
    sum += __shfl_xor(sum, 32, 64);
    if (g == 0) { redMS[wid][0][c] = m; redMS[wid][1][c] = sum; }
    __syncthreads();

    // flash combine across the 4 k-strips
    float m0 = redMS[0][0][c], m1 = redMS[1][0][c], m2 = redMS[2][0][c], m3 = redMS[3][0][c];
    float M = fmaxf(fmaxf(m0, m1), fmaxf(m2, m3));
    float S = redMS[0][1][c] * __expf(m0 - M) + redMS[1][1][c] * __expf(m1 - M)
            + redMS[2][1][c] * __expf(m2 - M) + redMS[3][1][c] * __expf(m3 - M);
    const float fw = __expf(m - M) / S;   // scale for this wave's p_local

    // fused normalize + attn store + pack + shfl redistribute + PV MFMA.
    // B[j] of the PV fragment = pk{kf=2ch+gd2}[j&1] taken from lane srcA/srcB.
    const int srcA = c + 32 * (g & 1);
    const int srcB = srcA + 16;
    const int gd2 = g >> 1;
    f32x4 o0 = (f32x4){0.f, 0.f, 0.f, 0.f};
    f32x4 o1 = (f32x4){0.f, 0.f, 0.f, 0.f};
    const unsigned short* vb0 = Vt + (size_t)(bh * 32 + c) * 1024 + kstrip;
    const unsigned short* vb1 = vb0 + 16 * 1024;
    float* arow = attn_out + bh_u + (size_t)q * S_;
    #pragma unroll
    for (int ch = 0; ch < 8; ++ch) {
        unsigned int p0[2], p1[2];
        #pragma unroll
        for (int kk = 0; kk < 2; ++kk) {
            const int kf = 2 * ch + kk;
            int k0 = kstrip + kf * 16 + g * 4;
            f32x4 a;
            #pragma unroll
            for (int r = 0; r < 4; ++r) a[r] = s[kf][r] * fw;
            *(f32x4*)(arow + k0) = a;
            unsigned int w0 = __builtin_amdgcn_perm(__float_as_uint(a[1]), __float_as_uint(a[0]), 0x07060302u);
            unsigned int w1 = __builtin_amdgcn_perm(__float_as_uint(a[3]), __float_as_uint(a[2]), 0x07060302u);
            if (kk == 0) { p0[0] = w0; p0[1] = w1; }
            else         { p1[0] = w0; p1[1] = w1; }
        }
        unsigned int b0A = (unsigned int)__shfl((int)p0[0], srcA, 64);
        unsigned int b1A = (unsigned int)__shfl((int)p0[1], srcA, 64);
        unsigned int b0B = (unsigned int)__shfl((int)p0[0], srcB, 64);
        unsigned int b1B = (unsigned int)__shfl((int)p0[1], srcB, 64);
        unsigned int c0A = (unsigned int)__shfl((int)p1[0], srcA, 64);
        unsigned int c1A = (unsigned int)__shfl((int)p1[1], srcA, 64);
        unsigned int c0B = (unsigned int)__shfl((int)p1[0], srcB, 64);
        unsigned int c1B = (unsigned int)__shfl((int)p1[1], srcB, 64);
        union { u32x4 u; short8 h; } bb;
        bb.u[0] = gd2 ? c0A : b0A;
        bb.u[1] = gd2 ? c1A : b1A;
        bb.u[2] = gd2 ? c0B : b0B;
        bb.u[3] = gd2 ? c1B : b1B;
        short8 A0 = *(const short8*)(vb0 + ch * 32 + g * 8);
        short8 A1 = *(const short8*)(vb1 + ch * 32 + g * 8);
        o0 = __builtin_amdgcn_mfma_f32_16x16x32_bf16(A0, bb.h, o0, 0, 0, 0);
        o1 = __builtin_amdgcn_mfma_f32_16x16x32_bf16(A1, bb.h, o1, 0, 0, 0);
    }
    // partial O^T: lane holds q = c, d = g*4+r (o0) / 16+g*4+r (o1)
    *(f32x4*)(&Ored[(wid * 16 + c) * 36 + g * 4]) = o0;
    *(f32x4*)(&Ored[(wid * 16 + c) * 36 + 16 + g * 4]) = o1;
    __syncthreads();

    // final 4-way reduce + store: thread t -> q = t>>4, d-pair = (t&15)*2
    const int qq = tid >> 4;
    const int dd = (tid & 15) * 2;
    float v0 = 0.f, v1 = 0.f;
    #pragma unroll
    for (int w = 0; w < 4; ++w) {
        v0 += Ored[(w * 16 + qq) * 36 + dd];
        v1 += Ored[(w * 16 + qq) * 36 + dd + 1];
    }
    const int b = bh >> 3, h = bh & 7;
    f32x2 vv = {v0, v1};
    *(f32x2*)(out_buf + ((size_t)(b * 1024 + qbase + qq)) * 256 + h * 32 + dd) = vv;
}

// ---------------- Kernel 3: output projection ----------------
__global__ __launch_bounds__(256) void outproj_kernel(
    const float* __restrict__ xb, const float* __restrict__ Wo, float* __restrict__ outp)
{
    const int m0 = blockIdx.x * 64;
    const int n0 = blockIdx.y * 64;
    __shared__ float xs[64 * 68];
    __shared__ float ws[64 * 68];
    const int t = threadIdx.x;
    const int ty = t >> 4, tx = t & 15;
    float acc[4][4] = {};
    for (int kc = 0; kc < 256; kc += 64) {
        #pragma unroll
        for (int it = 0; it < 4; ++it) {
            int fi = t + it * 256;
            int row = fi >> 4, c4 = fi & 15;
            *(float4*)(&xs[row * 68 + c4 * 4]) = *(const float4*)(&xb[(size_t)(m0 + row) * 256 + kc + c4 * 4]);
            *(float4*)(&ws[row * 68 + c4 * 4]) = *(const float4*)(&Wo[(size_t)(n0 + row) * 256 + kc + c4 * 4]);
        }
        __syncthreads();
        #pragma unroll
        for (int k4 = 0; k4 < 16; ++k4) {
            float4 a4[4], b4[4];
            #pragma unroll
            for (int i = 0; i < 4; ++i) a4[i] = *(const float4*)(&xs[(ty * 4 + i) * 68 + k4 * 4]);
            #pragma unroll
            for (int j = 0; j < 4; ++j) b4[j] = *(const float4*)(&ws[(tx * 4 + j) * 68 + k4 * 4]);
            #pragma unroll
            for (int i = 0; i < 4; ++i)
                #pragma unroll
                for (int j = 0; j < 4; ++j)
                    acc[i][j] += a4[i].x * b4[j].x + a4[i].y * b4[j].y + a4[i].z * b4[j].z + a4[i].w * b4[j].w;
        }
        __syncthreads();
    }
    #pragma unroll
    for (int i = 0; i < 4; ++i)
        #pragma unroll
        for (int j = 0; j < 4; ++j)
            outp[(size_t)(m0 + ty * 4 + i) * 128 + n0 + tx * 4 + j] = acc[i][j];
}

extern "C" void kernel_launch(void* const* d_in, const int* in_sizes, int n_in,
                              void* d_out, int out_size, void* d_ws, size_t ws_size,
                              hipStream_t stream)
{
    const float* query = (const float*)d_in[0];
    const float* U     = (const float*)d_in[1];
    const float* Wq    = (const float*)d_in[2];
    const float* Wk    = (const float*)d_in[3];
    const float* Wv    = (const float*)d_in[4];
    const float* Wo    = (const float*)d_in[5];

    float* output = (float*)d_out;                                 // B*S*D0
    float* attn   = (float*)d_out + (size_t)B_ * S_ * D0_;         // B*H*S*S

    const size_t NQK = (size_t)BH_ * S_ * 32;
    unsigned short* Qhi = (unsigned short*)d_ws;
    unsigned short* Qlo = Qhi + NQK;
    unsigned short* Khi = Qlo + NQK;
    unsigned short* Klo = Khi + NQK;
    unsigned short* Vt  = Klo + NQK;
    float* maskbias = (float*)(Vt + NQK);
    float* out_buf  = maskbias + (size_t)BH_ * S_;

    proj_kernel<<<dim3(128, 4, 3), 256, 0, stream>>>(query, Wq, Wk, Wv, Qhi, Qlo, Khi, Klo, Vt);
    mask_kernel<<<dim3(256), 256, 0, stream>>>(Qhi, Qlo, maskbias);
    attn_kernel<<<dim3(4096), 256, 0, stream>>>(Qhi, Qlo, Khi, Klo, Vt, maskbias, U, attn, out_buf);
    outproj_kernel<<<dim3(128, 2), 256, 0, stream>>>(out_buf, Wo, output);
}

// Round 6
// 261.736 us; speedup vs baseline: 1.3101x; 1.0381x over previous
//
#include <hip/hip_runtime.h>
#include <stdint.h>
#include <math.h>

#define B_ 8
#define S_ 1024
#define D0_ 128
#define D_ 256
#define H_ 8
#define HD_ 32
#define BH_ (B_*H_)

typedef __attribute__((ext_vector_type(8))) short short8;
typedef __attribute__((ext_vector_type(4))) float f32x4;
typedef __attribute__((ext_vector_type(4))) unsigned int u32x4;
typedef __attribute__((ext_vector_type(2))) float f32x2;

__device__ __forceinline__ unsigned short f2bf(float x) {
    unsigned int u = __float_as_uint(x);
    u += 0x7FFFu + ((u >> 16) & 1u);
    return (unsigned short)(u >> 16);
}
__device__ __forceinline__ float bf2f(unsigned short s) {
    return __uint_as_float(((unsigned int)s) << 16);
}

// ---------------- Kernel 1: projections (fp32 VALU GEMM) ----------------
__global__ __launch_bounds__(256) void proj_kernel(
    const float* __restrict__ query,
    const float* __restrict__ Wq, const float* __restrict__ Wk, const float* __restrict__ Wv,
    unsigned short* __restrict__ Qhi, unsigned short* __restrict__ Qlo,
    unsigned short* __restrict__ Khi, unsigned short* __restrict__ Klo,
    unsigned short* __restrict__ Vt)
{
    const int z = blockIdx.z;
    const float* W = (z == 0) ? Wq : (z == 1) ? Wk : Wv;
    const int m0 = blockIdx.x * 64;
    const int n0 = blockIdx.y * 64;
    __shared__ float xs[64 * 68];
    __shared__ float ws[64 * 68];
    const int t = threadIdx.x;
    const int ty = t >> 4, tx = t & 15;
    float acc[4][4] = {};
    for (int kc = 0; kc < 128; kc += 64) {
        #pragma unroll
        for (int it = 0; it < 4; ++it) {
            int fi = t + it * 256;
            int row = fi >> 4, c4 = fi & 15;
            *(float4*)(&xs[row * 68 + c4 * 4]) = *(const float4*)(&query[(size_t)(m0 + row) * 128 + kc + c4 * 4]);
            *(float4*)(&ws[row * 68 + c4 * 4]) = *(const float4*)(&W[(size_t)(n0 + row) * 128 + kc + c4 * 4]);
        }
        __syncthreads();
        #pragma unroll
        for (int k4 = 0; k4 < 16; ++k4) {
            float4 a4[4], b4[4];
            #pragma unroll
            for (int i = 0; i < 4; ++i) a4[i] = *(const float4*)(&xs[(ty * 4 + i) * 68 + k4 * 4]);
            #pragma unroll
            for (int j = 0; j < 4; ++j) b4[j] = *(const float4*)(&ws[(tx * 4 + j) * 68 + k4 * 4]);
            #pragma unroll
            for (int i = 0; i < 4; ++i)
                #pragma unroll
                for (int j = 0; j < 4; ++j)
                    acc[i][j] += a4[i].x * b4[j].x + a4[i].y * b4[j].y + a4[i].z * b4[j].z + a4[i].w * b4[j].w;
        }
        __syncthreads();
    }
    #pragma unroll
    for (int i = 0; i < 4; ++i) {
        int m = m0 + ty * 4 + i;
        int b = m >> 10, s = m & 1023;
        #pragma unroll
        for (int j = 0; j < 4; ++j) {
            int o = n0 + tx * 4 + j;
            int h = o >> 5, d = o & 31;
            int bh = b * 8 + h;
            float y = acc[i][j];
            if (z < 2) {
                unsigned short hi = f2bf(y);
                unsigned short lo = f2bf(y - bf2f(hi));
                size_t idx = ((size_t)(bh * 1024 + s)) * 32 + d;
                if (z == 0) { Qhi[idx] = hi; Qlo[idx] = lo; }
                else        { Khi[idx] = hi; Klo[idx] = lo; }
            } else {
                Vt[((size_t)(bh * 32 + d)) * 1024 + s] = f2bf(y);
            }
        }
    }
}

// ---------------- Kernel 1b: mask bias from Q row sums ----------------
__global__ void mask_kernel(const unsigned short* __restrict__ Qhi,
                            const unsigned short* __restrict__ Qlo,
                            float* __restrict__ maskbias)
{
    int r = blockIdx.x * blockDim.x + threadIdx.x;
    if (r >= BH_ * S_) return;
    const unsigned short* ph = Qhi + (size_t)r * 32;
    const unsigned short* pl = Qlo + (size_t)r * 32;
    float s = 0.f;
    #pragma unroll
    for (int d = 0; d < 32; ++d) s += bf2f(ph[d]) + bf2f(pl[d]);
    maskbias[r] = (s != 0.0f) ? 0.0f : -INFINITY;
}

// ---------------- Kernel 2: fused attention, register-resident P ----------------
// grid 4096 = 64 (b,h) x 64 q-tiles of 16 rows; block 256 = 4 waves.
// Wave w owns key strip [256w, 256w+256). QK^T swapped: mfma(K, Q) -> lane holds
// S^T[k][q], q = c = lane&15, k = kstrip + kf*16 + g*4 + r.
// R5 post-mortem: phase-serialized memory access (2.1 of 6.3 TB/s). Fixes:
//  (1) all 16 U loads hoisted ABOVE the QK loop -> U stream overlaps MFMA phase
//  (2) attn stores deferred to kernel tail: PV consumes RAW p_local, o *= fw
//      after (PV output col = q = c, same index as fw) -> mid-block barrier no
//      longer drains 16KB/wave of HBM stores.
// Register math: u[16] f32x4 (64) + s[16] f32x4 (64) + K/Q/misc ~40 => ~164;
// launch_bounds(256,3) gives 170/wave budget (256,4's 128 would re-spill, R4).
__global__ __launch_bounds__(256, 3) void attn_kernel(
    const unsigned short* __restrict__ Qhi, const unsigned short* __restrict__ Qlo,
    const unsigned short* __restrict__ Khi, const unsigned short* __restrict__ Klo,
    const unsigned short* __restrict__ Vt, const float* __restrict__ maskbias,
    const float* __restrict__ U, float* __restrict__ attn_out, float* __restrict__ out_buf)
{
    __shared__ float Ored[4 * 16 * 36];     // [wave][q(16)][d(32)+pad4]
    __shared__ float redMS[4][2][16];       // per-wave (m_w, s_w) per q

    const int bid = blockIdx.x;
    const int swz = (bid & 7) * 512 + (bid >> 3);   // XCD-contiguous bh
    const int bh = swz >> 6;
    const int qbase = (swz & 63) << 4;
    const int tid = threadIdx.x;
    const int wid = tid >> 6;
    const int c = tid & 15;
    const int g = (tid >> 4) & 3;
    const int kstrip = wid << 8;

    const size_t bh_qk = (size_t)bh * S_ * 32;
    const size_t bh_u = (size_t)bh * S_ * S_;
    const int q = qbase + c;

    // ---- U prefetch: 16 independent f32x4 loads issued before any compute ----
    const float* Urow = U + bh_u + (size_t)q * S_;
    f32x4 u[16];
    #pragma unroll
    for (int kf = 0; kf < 16; ++kf)
        u[kf] = *(const f32x4*)(Urow + kstrip + kf * 16 + g * 4);

    // Q fragment (B operand: col q = c, elements d = g*8..g*8+7)
    short8 qh = *(const short8*)(Qhi + bh_qk + (size_t)q * 32 + 8 * g);
    short8 ql = *(const short8*)(Qlo + bh_qk + (size_t)q * 32 + 8 * g);

    f32x4 s[16];
    #pragma unroll
    for (int kf = 0; kf < 16; ++kf) s[kf] = (f32x4){0.f, 0.f, 0.f, 0.f};

    // QK^T swapped, hi/lo split (3 MFMAs per kf) — overlaps U arrival
    #pragma unroll
    for (int kf = 0; kf < 16; ++kf) {
        size_t koff = bh_qk + (size_t)(kstrip + kf * 16 + c) * 32 + 8 * g;
        short8 kh = *(const short8*)(Khi + koff);
        short8 kl = *(const short8*)(Klo + koff);
        s[kf] = __builtin_amdgcn_mfma_f32_16x16x32_bf16(kh, qh, s[kf], 0, 0, 0);
        s[kf] = __builtin_amdgcn_mfma_f32_16x16x32_bf16(kl, qh, s[kf], 0, 0, 0);
        s[kf] = __builtin_amdgcn_mfma_f32_16x16x32_bf16(kh, ql, s[kf], 0, 0, 0);
    }

    const float inv_scale = 0.17677669529663687f; // 1/sqrt(32)
    const float* mbrow = maskbias + bh * S_;
    #pragma unroll
    for (int kf = 0; kf < 16; ++kf) {
        int k0 = kstrip + kf * 16 + g * 4;
        f32x4 mb = *(const f32x4*)(mbrow + k0);
        #pragma unroll
        for (int r = 0; r < 4; ++r)
            s[kf][r] = (s[kf][r] + u[kf][r]) * inv_scale + mb[r];
    }

    // local (per-wave) softmax stats for this q = c
    float m = s[0][0];
    #pragma unroll
    for (int kf = 0; kf < 16; ++kf)
        #pragma unroll
        for (int r = 0; r < 4; ++r) m = fmaxf(m, s[kf][r]);
    m = fmaxf(m, __shfl_xor(m, 16, 64));
    m = fmaxf(m, __shfl_xor(m, 32, 64));
    m = fmaxf(m, -1e30f);   // guard fully-masked strip

    float sum = 0.f;
    #pragma unroll
    for (int kf = 0; kf < 16; ++kf)
        #pragma unroll
        for (int r = 0; r < 4; ++r) {
            float p = __expf(s[kf][r] - m);
            s[kf][r] = p;              // p_local
            sum += p;
        }
    sum += __shfl_xor(sum, 16, 64);
    sum += __shfl_xor(sum, 32, 64);
    if (g == 0) { redMS[wid][0][c] = m; redMS[wid][1][c] = sum; }
    __syncthreads();

    // flash combine across the 4 k-strips
    float m0 = redMS[0][0][c], m1 = redMS[1][0][c], m2 = redMS[2][0][c], m3 = redMS[3][0][c];
    float M = fmaxf(fmaxf(m0, m1), fmaxf(m2, m3));
    float S = redMS[0][1][c] * __expf(m0 - M) + redMS[1][1][c] * __expf(m1 - M)
            + redMS[2][1][c] * __expf(m2 - M) + redMS[3][1][c] * __expf(m3 - M);
    const float fw = __expf(m - M) / S;   // scale for this wave's p_local

    // PV on RAW p_local (no attn stores here); B-frags via in-wave shfl.
    const int srcA = c + 32 * (g & 1);
    const int srcB = srcA + 16;
    const int gd2 = g >> 1;
    f32x4 o0 = (f32x4){0.f, 0.f, 0.f, 0.f};
    f32x4 o1 = (f32x4){0.f, 0.f, 0.f, 0.f};
    const unsigned short* vb0 = Vt + (size_t)(bh * 32 + c) * 1024 + kstrip;
    const unsigned short* vb1 = vb0 + 16 * 1024;
    #pragma unroll
    for (int ch = 0; ch < 8; ++ch) {
        unsigned int p0[2], p1[2];
        p0[0] = __builtin_amdgcn_perm(__float_as_uint(s[2 * ch][1]), __float_as_uint(s[2 * ch][0]), 0x07060302u);
        p0[1] = __builtin_amdgcn_perm(__float_as_uint(s[2 * ch][3]), __float_as_uint(s[2 * ch][2]), 0x07060302u);
        p1[0] = __builtin_amdgcn_perm(__float_as_uint(s[2 * ch + 1][1]), __float_as_uint(s[2 * ch + 1][0]), 0x07060302u);
        p1[1] = __builtin_amdgcn_perm(__float_as_uint(s[2 * ch + 1][3]), __float_as_uint(s[2 * ch + 1][2]), 0x07060302u);
        unsigned int b0A = (unsigned int)__shfl((int)p0[0], srcA, 64);
        unsigned int b1A = (unsigned int)__shfl((int)p0[1], srcA, 64);
        unsigned int b0B = (unsigned int)__shfl((int)p0[0], srcB, 64);
        unsigned int b1B = (unsigned int)__shfl((int)p0[1], srcB, 64);
        unsigned int c0A = (unsigned int)__shfl((int)p1[0], srcA, 64);
        unsigned int c1A = (unsigned int)__shfl((int)p1[1], srcA, 64);
        unsigned int c0B = (unsigned int)__shfl((int)p1[0], srcB, 64);
        unsigned int c1B = (unsigned int)__shfl((int)p1[1], srcB, 64);
        union { u32x4 u; short8 h; } bb;
        bb.u[0] = gd2 ? c0A : b0A;
        bb.u[1] = gd2 ? c1A : b1A;
        bb.u[2] = gd2 ? c0B : b0B;
        bb.u[3] = gd2 ? c1B : b1B;
        short8 A0 = *(const short8*)(vb0 + ch * 32 + g * 8);
        short8 A1 = *(const short8*)(vb1 + ch * 32 + g * 8);
        o0 = __builtin_amdgcn_mfma_f32_16x16x32_bf16(A0, bb.h, o0, 0, 0, 0);
        o1 = __builtin_amdgcn_mfma_f32_16x16x32_bf16(A1, bb.h, o1, 0, 0, 0);
    }
    // scale by fw (PV col = q = c matches fw's q), then cross-wave reduce
    #pragma unroll
    for (int r = 0; r < 4; ++r) { o0[r] *= fw; o1[r] *= fw; }
    *(f32x4*)(&Ored[(wid * 16 + c) * 36 + g * 4]) = o0;
    *(f32x4*)(&Ored[(wid * 16 + c) * 36 + 16 + g * 4]) = o1;
    __syncthreads();   // only V loads (L2-fast) outstanding here

    // final 4-way reduce + store: thread t -> q = t>>4, d-pair = (t&15)*2
    const int qq = tid >> 4;
    const int dd = (tid & 15) * 2;
    float v0 = 0.f, v1 = 0.f;
    #pragma unroll
    for (int w = 0; w < 4; ++w) {
        v0 += Ored[(w * 16 + qq) * 36 + dd];
        v1 += Ored[(w * 16 + qq) * 36 + dd + 1];
    }
    const int b = bh >> 3, h = bh & 7;
    f32x2 vv = {v0, v1};
    *(f32x2*)(out_buf + ((size_t)(b * 1024 + qbase + qq)) * 256 + h * 32 + dd) = vv;

    // ---- tail: normalize + store attn (fire-and-forget, no barrier after) ----
    float* arow = attn_out + bh_u + (size_t)q * S_;
    #pragma unroll
    for (int kf = 0; kf < 16; ++kf) {
        int k0 = kstrip + kf * 16 + g * 4;
        f32x4 a;
        #pragma unroll
        for (int r = 0; r < 4; ++r) a[r] = s[kf][r] * fw;
        *(f32x4*)(arow + k0) = a;
    }
}

// ---------------- Kernel 3: output projection ----------------
__global__ __launch_bounds__(256) void outproj_kernel(
    const float* __restrict__ xb, const float* __restrict__ Wo, float* __restrict__ outp)
{
    const int m0 = blockIdx.x * 64;
    const int n0 = blockIdx.y * 64;
    __shared__ float xs[64 * 68];
    __shared__ float ws[64 * 68];
    const int t = threadIdx.x;
    const int ty = t >> 4, tx = t & 15;
    float acc[4][4] = {};
    for (int kc = 0; kc < 256; kc += 64) {
        #pragma unroll
        for (int it = 0; it < 4; ++it) {
            int fi = t + it * 256;
            int row = fi >> 4, c4 = fi & 15;
            *(float4*)(&xs[row * 68 + c4 * 4]) = *(const float4*)(&xb[(size_t)(m0 + row) * 256 + kc + c4 * 4]);
            *(float4*)(&ws[row * 68 + c4 * 4]) = *(const float4*)(&Wo[(size_t)(n0 + row) * 256 + kc + c4 * 4]);
        }
        __syncthreads();
        #pragma unroll
        for (int k4 = 0; k4 < 16; ++k4) {
            float4 a4[4], b4[4];
            #pragma unroll
            for (int i = 0; i < 4; ++i) a4[i] = *(const float4*)(&xs[(ty * 4 + i) * 68 + k4 * 4]);
            #pragma unroll
            for (int j = 0; j < 4; ++j) b4[j] = *(const float4*)(&ws[(tx * 4 + j) * 68 + k4 * 4]);
            #pragma unroll
            for (int i = 0; i < 4; ++i)
                #pragma unroll
                for (int j = 0; j < 4; ++j)
                    acc[i][j] += a4[i].x * b4[j].x + a4[i].y * b4[j].y + a4[i].z * b4[j].z + a4[i].w * b4[j].w;
        }
        __syncthreads();
    }
    #pragma unroll
    for (int i = 0; i < 4; ++i)
        #pragma unroll
        for (int j = 0; j < 4; ++j)
            outp[(size_t)(m0 + ty * 4 + i) * 128 + n0 + tx * 4 + j] = acc[i][j];
}

extern "C" void kernel_launch(void* const* d_in, const int* in_sizes, int n_in,
                              void* d_out, int out_size, void* d_ws, size_t ws_size,
                              hipStream_t stream)
{
    const float* query = (const float*)d_in[0];
    const float* U     = (const float*)d_in[1];
    const float* Wq    = (const float*)d_in[2];
    const float* Wk    = (const float*)d_in[3];
    const float* Wv    = (const float*)d_in[4];
    const float* Wo    = (const float*)d_in[5];

    float* output = (float*)d_out;                                 // B*S*D0
    float* attn   = (float*)d_out + (size_t)B_ * S_ * D0_;         // B*H*S*S

    const size_t NQK = (size_t)BH_ * S_ * 32;
    unsigned short* Qhi = (unsigned short*)d_ws;
    unsigned short* Qlo = Qhi + NQK;
    unsigned short* Khi = Qlo + NQK;
    unsigned short* Klo = Khi + NQK;
    unsigned short* Vt  = Klo + NQK;
    float* maskbias = (float*)(Vt + NQK);
    float* out_buf  = maskbias + (size_t)BH_ * S_;

    proj_kernel<<<dim3(128, 4, 3), 256, 0, stream>>>(query, Wq, Wk, Wv, Qhi, Qlo, Khi, Klo, Vt);
    mask_kernel<<<dim3(256), 256, 0, stream>>>(Qhi, Qlo, maskbias);
    attn_kernel<<<dim3(4096), 256, 0, stream>>>(Qhi, Qlo, Khi, Klo, Vt, maskbias, U, attn, out_buf);
    outproj_kernel<<<dim3(128, 2), 256, 0, stream>>>(out_buf, Wo, output);
}

// Round 7
// 259.408 us; speedup vs baseline: 1.3218x; 1.0090x over previous
//
#include <hip/hip_runtime.h>
#include <stdint.h>
#include <math.h>

#define B_ 8
#define S_ 1024
#define D0_ 128
#define D_ 256
#define H_ 8
#define HD_ 32
#define BH_ (B_*H_)

typedef __attribute__((ext_vector_type(8))) short short8;
typedef __attribute__((ext_vector_type(4))) float f32x4;
typedef __attribute__((ext_vector_type(4))) unsigned int u32x4;
typedef __attribute__((ext_vector_type(2))) float f32x2;

__device__ __forceinline__ unsigned short f2bf(float x) {
    unsigned int u = __float_as_uint(x);
    u += 0x7FFFu + ((u >> 16) & 1u);
    return (unsigned short)(u >> 16);
}
__device__ __forceinline__ float bf2f(unsigned short s) {
    return __uint_as_float(((unsigned int)s) << 16);
}

// ---------------- Kernel 1: projections (fp32 VALU GEMM) ----------------
// z=0: Q (hi/lo) + fused mask-bias rowsums; z=1: K (hi/lo); z=2: V transposed.
__global__ __launch_bounds__(256) void proj_kernel(
    const float* __restrict__ query,
    const float* __restrict__ Wq, const float* __restrict__ Wk, const float* __restrict__ Wv,
    unsigned short* __restrict__ Qhi, unsigned short* __restrict__ Qlo,
    unsigned short* __restrict__ Khi, unsigned short* __restrict__ Klo,
    unsigned short* __restrict__ Vt, float* __restrict__ maskbias)
{
    const int z = blockIdx.z;
    const float* W = (z == 0) ? Wq : (z == 1) ? Wk : Wv;
    const int m0 = blockIdx.x * 64;
    const int n0 = blockIdx.y * 64;
    __shared__ float xs[64 * 68];
    __shared__ float ws[64 * 68];
    __shared__ float msum[64][2];
    const int t = threadIdx.x;
    const int ty = t >> 4, tx = t & 15;
    if (z == 0 && t < 128) msum[t >> 1][t & 1] = 0.f;
    float acc[4][4] = {};
    for (int kc = 0; kc < 128; kc += 64) {
        #pragma unroll
        for (int it = 0; it < 4; ++it) {
            int fi = t + it * 256;
            int row = fi >> 4, c4 = fi & 15;
            *(float4*)(&xs[row * 68 + c4 * 4]) = *(const float4*)(&query[(size_t)(m0 + row) * 128 + kc + c4 * 4]);
            *(float4*)(&ws[row * 68 + c4 * 4]) = *(const float4*)(&W[(size_t)(n0 + row) * 128 + kc + c4 * 4]);
        }
        __syncthreads();
        #pragma unroll
        for (int k4 = 0; k4 < 16; ++k4) {
            float4 a4[4], b4[4];
            #pragma unroll
            for (int i = 0; i < 4; ++i) a4[i] = *(const float4*)(&xs[(ty * 4 + i) * 68 + k4 * 4]);
            #pragma unroll
            for (int j = 0; j < 4; ++j) b4[j] = *(const float4*)(&ws[(tx * 4 + j) * 68 + k4 * 4]);
            #pragma unroll
            for (int i = 0; i < 4; ++i)
                #pragma unroll
                for (int j = 0; j < 4; ++j)
                    acc[i][j] += a4[i].x * b4[j].x + a4[i].y * b4[j].y + a4[i].z * b4[j].z + a4[i].w * b4[j].w;
        }
        __syncthreads();
    }
    #pragma unroll
    for (int i = 0; i < 4; ++i) {
        int m = m0 + ty * 4 + i;
        int b = m >> 10, s = m & 1023;
        #pragma unroll
        for (int j = 0; j < 4; ++j) {
            int o = n0 + tx * 4 + j;
            int h = o >> 5, d = o & 31;
            int bh = b * 8 + h;
            float y = acc[i][j];
            if (z < 2) {
                unsigned short hi = f2bf(y);
                unsigned short lo = f2bf(y - bf2f(hi));
                size_t idx = ((size_t)(bh * 1024 + s)) * 32 + d;
                if (z == 0) { Qhi[idx] = hi; Qlo[idx] = lo; }
                else        { Khi[idx] = hi; Klo[idx] = lo; }
            } else {
                Vt[((size_t)(bh * 32 + d)) * 1024 + s] = f2bf(y);
            }
        }
    }
    if (z == 0) {
        // fused mask rowsums: cols [n0,n0+64) = heads n0/32, n0/32+1 (full 32-d each)
        #pragma unroll
        for (int i = 0; i < 4; ++i) {
            float ps = acc[i][0] + acc[i][1] + acc[i][2] + acc[i][3];
            atomicAdd(&msum[ty * 4 + i][tx >> 3], ps);
        }
        __syncthreads();
        if (t < 128) {
            int row = t >> 1, hh = t & 1;
            int m = m0 + row;
            int b = m >> 10, s = m & 1023;
            int bh = b * 8 + (n0 >> 5) + hh;
            maskbias[bh * 1024 + s] = (msum[row][hh] != 0.0f) ? 0.0f : -INFINITY;
        }
    }
}

// ---------------- Kernel 2: fused attention, register-resident P ----------------
// grid 4096 = 64 (b,h) x 64 q-tiles of 16 rows; block 256 = 4 waves.
// Wave w owns key strip [256w, 256w+256). QK^T swapped: mfma(K, Q) -> lane holds
// S^T[k][q], q = c = lane&15, k = kstrip + kf*16 + g*4 + r.
// R6 post-mortem: occupancy fell 41->31% at (256,3); back to (256,4).
// U loads now feed the MFMA C-input directly (s[kf] init = U) -> no separate
// u[] array (64 fewer live regs) and per-kf interleaved waits instead of a
// bulk drain. attn stores remain at the kernel tail (R6 win).
__global__ __launch_bounds__(256, 4) void attn_kernel(
    const unsigned short* __restrict__ Qhi, const unsigned short* __restrict__ Qlo,
    const unsigned short* __restrict__ Khi, const unsigned short* __restrict__ Klo,
    const unsigned short* __restrict__ Vt, const float* __restrict__ maskbias,
    const float* __restrict__ U, float* __restrict__ attn_out, float* __restrict__ out_buf)
{
    __shared__ float Ored[4 * 16 * 36];     // [wave][q(16)][d(32)+pad4]
    __shared__ float redMS[4][2][16];       // per-wave (m_w, s_w) per q

    const int bid = blockIdx.x;
    const int swz = (bid & 7) * 512 + (bid >> 3);   // XCD-contiguous bh
    const int bh = swz >> 6;
    const int qbase = (swz & 63) << 4;
    const int tid = threadIdx.x;
    const int wid = tid >> 6;
    const int c = tid & 15;
    const int g = (tid >> 4) & 3;
    const int kstrip = wid << 8;

    const size_t bh_qk = (size_t)bh * S_ * 32;
    const size_t bh_u = (size_t)bh * S_ * S_;
    const int q = qbase + c;

    // ---- U loads straight into the score accumulators (MFMA C-init) ----
    const float* Urow = U + bh_u + (size_t)q * S_;
    f32x4 s[16];
    #pragma unroll
    for (int kf = 0; kf < 16; ++kf)
        s[kf] = *(const f32x4*)(Urow + kstrip + kf * 16 + g * 4);

    // Q fragment (B operand: col q = c, elements d = g*8..g*8+7)
    short8 qh = *(const short8*)(Qhi + bh_qk + (size_t)q * 32 + 8 * g);
    short8 ql = *(const short8*)(Qlo + bh_qk + (size_t)q * 32 + 8 * g);

    // QK^T swapped, hi/lo split (3 MFMAs per kf); C-in = U so s = qk + u
    #pragma unroll
    for (int kf = 0; kf < 16; ++kf) {
        size_t koff = bh_qk + (size_t)(kstrip + kf * 16 + c) * 32 + 8 * g;
        short8 kh = *(const short8*)(Khi + koff);
        short8 kl = *(const short8*)(Klo + koff);
        s[kf] = __builtin_amdgcn_mfma_f32_16x16x32_bf16(kh, qh, s[kf], 0, 0, 0);
        s[kf] = __builtin_amdgcn_mfma_f32_16x16x32_bf16(kl, qh, s[kf], 0, 0, 0);
        s[kf] = __builtin_amdgcn_mfma_f32_16x16x32_bf16(kh, ql, s[kf], 0, 0, 0);
    }

    const float inv_scale = 0.17677669529663687f; // 1/sqrt(32)
    const float* mbrow = maskbias + bh * S_;
    #pragma unroll
    for (int kf = 0; kf < 16; ++kf) {
        int k0 = kstrip + kf * 16 + g * 4;
        f32x4 mb = *(const f32x4*)(mbrow + k0);
        #pragma unroll
        for (int r = 0; r < 4; ++r)
            s[kf][r] = s[kf][r] * inv_scale + mb[r];
    }

    // local (per-wave) softmax stats for this q = c
    float m = s[0][0];
    #pragma unroll
    for (int kf = 0; kf < 16; ++kf)
        #pragma unroll
        for (int r = 0; r < 4; ++r) m = fmaxf(m, s[kf][r]);
    m = fmaxf(m, __shfl_xor(m, 16, 64));
    m = fmaxf(m, __shfl_xor(m, 32, 64));
    m = fmaxf(m, -1e30f);   // guard fully-masked strip

    float sum = 0.f;
    #pragma unroll
    for (int kf = 0; kf < 16; ++kf)
        #pragma unroll
        for (int r = 0; r < 4; ++r) {
            float p = __expf(s[kf][r] - m);
            s[kf][r] = p;              // p_local
            sum += p;
        }
    sum += __shfl_xor(sum, 16, 64);
    sum += __shfl_xor(sum, 32, 64);
    if (g == 0) { redMS[wid][0][c] = m; redMS[wid][1][c] = sum; }
    __syncthreads();

    // flash combine across the 4 k-strips
    float m0 = redMS[0][0][c], m1 = redMS[1][0][c], m2 = redMS[2][0][c], m3 = redMS[3][0][c];
    float M = fmaxf(fmaxf(m0, m1), fmaxf(m2, m3));
    float S = redMS[0][1][c] * __expf(m0 - M) + redMS[1][1][c] * __expf(m1 - M)
            + redMS[2][1][c] * __expf(m2 - M) + redMS[3][1][c] * __expf(m3 - M);
    const float fw = __expf(m - M) / S;   // scale for this wave's p_local

    // PV on RAW p_local; B-frags via in-wave shfl redistribution
    const int srcA = c + 32 * (g & 1);
    const int srcB = srcA + 16;
    const int gd2 = g >> 1;
    f32x4 o0 = (f32x4){0.f, 0.f, 0.f, 0.f};
    f32x4 o1 = (f32x4){0.f, 0.f, 0.f, 0.f};
    const unsigned short* vb0 = Vt + (size_t)(bh * 32 + c) * 1024 + kstrip;
    const unsigned short* vb1 = vb0 + 16 * 1024;
    #pragma unroll
    for (int ch = 0; ch < 8; ++ch) {
        unsigned int p0[2], p1[2];
        p0[0] = __builtin_amdgcn_perm(__float_as_uint(s[2 * ch][1]), __float_as_uint(s[2 * ch][0]), 0x07060302u);
        p0[1] = __builtin_amdgcn_perm(__float_as_uint(s[2 * ch][3]), __float_as_uint(s[2 * ch][2]), 0x07060302u);
        p1[0] = __builtin_amdgcn_perm(__float_as_uint(s[2 * ch + 1][1]), __float_as_uint(s[2 * ch + 1][0]), 0x07060302u);
        p1[1] = __builtin_amdgcn_perm(__float_as_uint(s[2 * ch + 1][3]), __float_as_uint(s[2 * ch + 1][2]), 0x07060302u);
        unsigned int b0A = (unsigned int)__shfl((int)p0[0], srcA, 64);
        unsigned int b1A = (unsigned int)__shfl((int)p0[1], srcA, 64);
        unsigned int b0B = (unsigned int)__shfl((int)p0[0], srcB, 64);
        unsigned int b1B = (unsigned int)__shfl((int)p0[1], srcB, 64);
        unsigned int c0A = (unsigned int)__shfl((int)p1[0], srcA, 64);
        unsigned int c1A = (unsigned int)__shfl((int)p1[1], srcA, 64);
        unsigned int c0B = (unsigned int)__shfl((int)p1[0], srcB, 64);
        unsigned int c1B = (unsigned int)__shfl((int)p1[1], srcB, 64);
        union { u32x4 u; short8 h; } bb;
        bb.u[0] = gd2 ? c0A : b0A;
        bb.u[1] = gd2 ? c1A : b1A;
        bb.u[2] = gd2 ? c0B : b0B;
        bb.u[3] = gd2 ? c1B : b1B;
        short8 A0 = *(const short8*)(vb0 + ch * 32 + g * 8);
        short8 A1 = *(const short8*)(vb1 + ch * 32 + g * 8);
        o0 = __builtin_amdgcn_mfma_f32_16x16x32_bf16(A0, bb.h, o0, 0, 0, 0);
        o1 = __builtin_amdgcn_mfma_f32_16x16x32_bf16(A1, bb.h, o1, 0, 0, 0);
    }
    // scale by fw (PV col = q = c matches fw's q), then cross-wave reduce
    #pragma unroll
    for (int r = 0; r < 4; ++r) { o0[r] *= fw; o1[r] *= fw; }
    *(f32x4*)(&Ored[(wid * 16 + c) * 36 + g * 4]) = o0;
    *(f32x4*)(&Ored[(wid * 16 + c) * 36 + 16 + g * 4]) = o1;
    __syncthreads();   // only V loads (L2-fast) outstanding here

    // final 4-way reduce + store: thread t -> q = t>>4, d-pair = (t&15)*2
    const int qq = tid >> 4;
    const int dd = (tid & 15) * 2;
    float v0 = 0.f, v1 = 0.f;
    #pragma unroll
    for (int w = 0; w < 4; ++w) {
        v0 += Ored[(w * 16 + qq) * 36 + dd];
        v1 += Ored[(w * 16 + qq) * 36 + dd + 1];
    }
    const int b = bh >> 3, h = bh & 7;
    f32x2 vv = {v0, v1};
    *(f32x2*)(out_buf + ((size_t)(b * 1024 + qbase + qq)) * 256 + h * 32 + dd) = vv;

    // ---- tail: normalize + store attn (fire-and-forget, no barrier after) ----
    float* arow = attn_out + bh_u + (size_t)q * S_;
    #pragma unroll
    for (int kf = 0; kf < 16; ++kf) {
        int k0 = kstrip + kf * 16 + g * 4;
        f32x4 a;
        #pragma unroll
        for (int r = 0; r < 4; ++r) a[r] = s[kf][r] * fw;
        *(f32x4*)(arow + k0) = a;
    }
}

// ---------------- Kernel 3: output projection ----------------
__global__ __launch_bounds__(256) void outproj_kernel(
    const float* __restrict__ xb, const float* __restrict__ Wo, float* __restrict__ outp)
{
    const int m0 = blockIdx.x * 64;
    const int n0 = blockIdx.y * 64;
    __shared__ float xs[64 * 68];
    __shared__ float ws[64 * 68];
    const int t = threadIdx.x;
    const int ty = t >> 4, tx = t & 15;
    float acc[4][4] = {};
    for (int kc = 0; kc < 256; kc += 64) {
        #pragma unroll
        for (int it = 0; it < 4; ++it) {
            int fi = t + it * 256;
            int row = fi >> 4, c4 = fi & 15;
            *(float4*)(&xs[row * 68 + c4 * 4]) = *(const float4*)(&xb[(size_t)(m0 + row) * 256 + kc + c4 * 4]);
            *(float4*)(&ws[row * 68 + c4 * 4]) = *(const float4*)(&Wo[(size_t)(n0 + row) * 256 + kc + c4 * 4]);
        }
        __syncthreads();
        #pragma unroll
        for (int k4 = 0; k4 < 16; ++k4) {
            float4 a4[4], b4[4];
            #pragma unroll
            for (int i = 0; i < 4; ++i) a4[i] = *(const float4*)(&xs[(ty * 4 + i) * 68 + k4 * 4]);
            #pragma unroll
            for (int j = 0; j < 4; ++j) b4[j] = *(const float4*)(&ws[(tx * 4 + j) * 68 + k4 * 4]);
            #pragma unroll
            for (int i = 0; i < 4; ++i)
                #pragma unroll
                for (int j = 0; j < 4; ++j)
                    acc[i][j] += a4[i].x * b4[j].x + a4[i].y * b4[j].y + a4[i].z * b4[j].z + a4[i].w * b4[j].w;
        }
        __syncthreads();
    }
    #pragma unroll
    for (int i = 0; i < 4; ++i)
        #pragma unroll
        for (int j = 0; j < 4; ++j)
            outp[(size_t)(m0 + ty * 4 + i) * 128 + n0 + tx * 4 + j] = acc[i][j];
}

extern "C" void kernel_launch(void* const* d_in, const int* in_sizes, int n_in,
                              void* d_out, int out_size, void* d_ws, size_t ws_size,
                              hipStream_t stream)
{
    const float* query = (const float*)d_in[0];
    const float* U     = (const float*)d_in[1];
    const float* Wq    = (const float*)d_in[2];
    const float* Wk    = (const float*)d_in[3];
    const float* Wv    = (const float*)d_in[4];
    const float* Wo    = (const float*)d_in[5];

    float* output = (float*)d_out;                                 // B*S*D0
    float* attn   = (float*)d_out + (size_t)B_ * S_ * D0_;         // B*H*S*S

    const size_t NQK = (size_t)BH_ * S_ * 32;
    unsigned short* Qhi = (unsigned short*)d_ws;
    unsigned short* Qlo = Qhi + NQK;
    unsigned short* Khi = Qlo + NQK;
    unsigned short* Klo = Khi + NQK;
    unsigned short* Vt  = Klo + NQK;
    float* maskbias = (float*)(Vt + NQK);
    float* out_buf  = maskbias + (size_t)BH_ * S_;

    proj_kernel<<<dim3(128, 4, 3), 256, 0, stream>>>(query, Wq, Wk, Wv, Qhi, Qlo, Khi, Klo, Vt, maskbias);
    attn_kernel<<<dim3(4096), 256, 0, stream>>>(Qhi, Qlo, Khi, Klo, Vt, maskbias, U, attn, out_buf);
    outproj_kernel<<<dim3(128, 2), 256, 0, stream>>>(out_buf, Wo, output);
}